// Round 6
// baseline (570.339 us; speedup 1.0000x reference)
//
#include <hip/hip_runtime.h>
#include <stdint.h>

// Problem constants (match reference)
#define BB     4
#define CC     32
#define HH     32
#define WW     1024
#define PATCH  21
#define RAD    10
#define PADW   20                 // DIL*RAD : max displacement
#define CHUNKC 2                  // channels staged per pass (R3/R5-proven envelope)
#define NP     (CC / CHUNKC)      // 16 passes
#define NGR    266                // float4 granules per padded row ((1024+40)/4)
#define ROWF   (NGR * 4)          // 1064 floats per channel row
#define BUFF   (CHUNKC * ROWF)    // 2128 floats per buffer (8.5 KB)
#define CSTR   (HH * WW)          // channel stride (also the out pj stride)

// R5 POST-MORTEM: body was right (VGPR=48, no spill, WRITE=output only) but
// FETCH 151->500 MB: the 48 blocks sharing one x2 row (8 slots x 6 z) were
// strided 72/2304 apart in linear id -> different XCDs, different times -> HBM
// re-fetch. R6: SAME body, remapped 1-D dispatch: lid%8 = XCD slot = row%8
// with row = 4*r2i + b. All 48 sharers: same XCD, 384-id window. Each XCD is
// pinned to one b + one r2-parity -> hot set x1[b] (4MB) + x2 slice fits L2.
typedef __attribute__((address_space(3))) uint32_t lds_u32_t;
typedef __attribute__((address_space(1))) const uint32_t glb_u32_t;

// Involution on granule index: for 8 consecutive even (or odd) logical slots,
// sigma's image is a complete residue system mod 8 -> conflict-free b128 reads.
// Closed on the never-staged OOB slot set {0..4, 261..265} (264<->265).
__device__ __forceinline__ int swz(int s) { return s ^ ((s >> 3) & 1); }

// DMA CHUNKC channels of one x2 row into sbuf (linear LDS dest = wave-uniform
// base + lane*16; swizzle realized by fetching global granule swz(q) into
// physical slot q — rule #21). Fully-OOB granules skipped -> keep prologue zeros.
__device__ __forceinline__ void stage_dma(const float* __restrict__ src0,
                                          float* __restrict__ sbuf, int tid) {
#pragma unroll
    for (int t = 0; t < 3; t++) {
        const int idx = tid + t * 256;
        if (idx < CHUNKC * NGR) {
            const int c  = (idx >= NGR) ? 1 : 0;
            const int q  = idx - c * NGR;
            const int gq = swz(q);
            const int base_gran = (tid & ~63) + t * 256;   // wave-uniform
            lds_u32_t* dst = (lds_u32_t*)(sbuf + base_gran * 4);
            const float* src = src0 + (size_t)c * CSTR + (gq * 4 - PADW);
            if (gq >= 5 && gq <= 260)
                __builtin_amdgcn_global_load_lds((glb_u32_t*)src, dst, 16, 0, 0);
        }
    }
}

// Block: 256 threads = 128 w-positions (Wout=8) x 2 tap-halves.
// Work decode from 1-D lid (see header comment). Chain for fixed (b,r2):
// elements e -> (pi = pi_hi - e, h = h0 + 2e); slot s owns {2s, 2s+1}
// (h rows sharing x2 row r2). Taps: pj = 4z + 2*th2 + j, j in {0,1}.
__global__ __launch_bounds__(256, 8)
void corr_kernel(const float* __restrict__ x1, const float* __restrict__ x2,
                 float* __restrict__ out) {
    __shared__ float sx2[2 * BUFF + 16];   // +16: masked tap-21 over-read pad

    const int tid = threadIdx.x;
    const int tw  = tid & 127;
    const int th2 = tid >> 7;              // wave-uniform (waves 0,1 vs 2,3)

    // ---- dispatch decode: lid -> (r2, b, s, z) with XCD pinning ----
    const int lid    = blockIdx.x;         // 0..13823
    const int xcd    = lid & 7;            // target XCD slot (m09 round-robin)
    const int t8     = lid >> 3;           // 0..1727
    const int sharer = t8 % 48;            // 48 sharers of one (b,r2) row
    const int rowd   = t8 / 48;            // 0..35
    const int row    = rowd * 8 + xcd;     // 0..287 ; row = 4*r2i + b
    const int r2i    = row >> 2;           // 0..71
    const int b      = row & 3;
    const int s      = sharer & 7;         // chain pair-slot
    const int z      = sharer >> 3;        // tap group 0..5
    const int r2     = r2i - PADW;         // -20..51

    const int pi_hi = min(20, (r2 + 20) >> 1);
    const int pi_lo = max(0, (r2 - 10) >> 1);
    const int L     = pi_hi - pi_lo + 1;        // chain length (1..16)
    const int e0    = 2 * s;
    if (e0 >= L) return;                        // empty slot: uniform exit

    const int  pi0  = pi_hi - e0;
    const int  h0   = r2 + 20 - 2 * pi0;        // in [0,31] by construction
    const bool has1 = (e0 + 1) < L;
    const int  pi1  = pi0 - 1;
    const int  h1   = h0 + 2;

    const int  pjb    = 4 * z + 2 * th2;        // even tap base
    const bool st0    = (pjb     <= 20);        // false only z=5,th2=1
    const bool st1    = (pjb + 1 <= 20);        // false for z=5
    const bool active = st0;                    // inactive waves: stage+barrier only
    const int  w8     = tw * 8;

    float* out0 = out + (((size_t)(b * PATCH * PATCH + pi0 * PATCH + pjb)) * HH + h0) * WW + w8;
    float* out1 = out + (((size_t)(b * PATCH * PATCH + pi1 * PATCH + pjb)) * HH + h1) * WW + w8;

    if ((unsigned)r2 >= (unsigned)HH) {
        // x2 row OOB: these (h,pi) outputs are zero for ALL taps. No barriers run.
        float4 zv = make_float4(0.f, 0.f, 0.f, 0.f);
        if (active) {
#pragma unroll
            for (int j = 0; j < 2; j++) {
                if (j == 0 ? st0 : st1) {
                    *(float4*)(out0 + (size_t)j * CSTR)     = zv;
                    *(float4*)(out0 + (size_t)j * CSTR + 4) = zv;
                    if (has1) {
                        *(float4*)(out1 + (size_t)j * CSTR)     = zv;
                        *(float4*)(out1 + (size_t)j * CSTR + 4) = zv;
                    }
                }
            }
        }
        return;
    }

    // Prologue: zero never-staged OOB slots of all 4 rows (2 buf x 2 ch).
    if (tid < 40) {
        const int rr = tid / 10, g = tid % 10;
        const int slot = (g < 5) ? g : (256 + g);   // {0..4, 261..265}
        *(float4*)(sx2 + rr * ROWF + 4 * slot) = make_float4(0.f, 0.f, 0.f, 0.f);
    }

    // Window granule base: padded col p = 8*tw + 2*pjb + (k + 2j); gb = 2tw + pjb/2.
    const int g0 = active ? (2 * tw + 2 * z + th2) : (2 * tw);
    int ps0 = 4 * swz(g0), ps1 = 4 * swz(g0 + 1), ps2 = 4 * swz(g0 + 2);

    const float* x2base = x2 + ((size_t)(b * CC) * HH + r2) * WW;
    const float* x1p0   = x1 + ((size_t)(b * CC) * HH + h0) * WW + w8;
    const float* x1p1   = has1 ? (x1p0 + 2 * WW) : x1p0;   // clamp: unused if !has1

    stage_dma(x2base, sx2, tid);     // chunk 0 -> buf 0
    __syncthreads();                 // drains DMA + prologue zeros

    float acc0[2][8], acc1[2][8];
#pragma unroll
    for (int j = 0; j < 2; j++)
#pragma unroll
        for (int k = 0; k < 8; k++) { acc0[j][k] = 0.f; acc1[j][k] = 0.f; }

    for (int p = 0; p < NP; p++) {
        if (p + 1 < NP)   // issue next chunk's DMA before computing this one
            stage_dma(x2base + (size_t)(p + 1) * CHUNKC * CSTR,
                      sx2 + ((p + 1) & 1) * BUFF, tid);
        if (active) {
            const float* buf = sx2 + (p & 1) * BUFF;
#pragma unroll
            for (int c = 0; c < CHUNKC; c++) {
                const float* row_p = buf + c * ROWF;
                float win[12];
                *(float4*)&win[0] = *(const float4*)(row_p + ps0);
                *(float4*)&win[4] = *(const float4*)(row_p + ps1);
                *(float4*)&win[8] = *(const float4*)(row_p + ps2);

                const float* xa = x1p0 + (size_t)(CHUNKC * p + c) * CSTR;
                const float* xb = x1p1 + (size_t)(CHUNKC * p + c) * CSTR;
                float4 a00 = *(const float4*)xa, a01 = *(const float4*)(xa + 4);
                float4 a10 = *(const float4*)xb, a11 = *(const float4*)(xb + 4);
                const float a0[8] = {a00.x, a00.y, a00.z, a00.w, a01.x, a01.y, a01.z, a01.w};
                const float a1[8] = {a10.x, a10.y, a10.z, a10.w, a11.x, a11.y, a11.z, a11.w};

                // tap j, output w8+k -> window float k + 2j (static, max 9)
#pragma unroll
                for (int j = 0; j < 2; j++)
#pragma unroll
                    for (int k = 0; k < 8; k++) {
                        const float wv = win[k + 2 * j];
                        acc0[j][k] = fmaf(a0[k], wv, acc0[j][k]);
                        acc1[j][k] = fmaf(a1[k], wv, acc1[j][k]);
                    }
            }
        }
        if (p + 1 < NP) __syncthreads();
    }

    if (!active) return;

    const float inv_c = 1.0f / (float)CC;
#pragma unroll
    for (int j = 0; j < 2; j++) {
        if (j == 0 ? st0 : st1) {
            float4 o0, o1, q0, q1;
            float* po0 = (float*)&o0; float* po1 = (float*)&o1;
            float* pq0 = (float*)&q0; float* pq1 = (float*)&q1;
#pragma unroll
            for (int k = 0; k < 4; k++) {
                float v0 = acc0[j][k]     * inv_c;
                float v1 = acc0[j][4 + k] * inv_c;
                float u0 = acc1[j][k]     * inv_c;
                float u1 = acc1[j][4 + k] * inv_c;
                po0[k] = v0 > 0.f ? v0 : 0.1f * v0;
                po1[k] = v1 > 0.f ? v1 : 0.1f * v1;
                pq0[k] = u0 > 0.f ? u0 : 0.1f * u0;
                pq1[k] = u1 > 0.f ? u1 : 0.1f * u1;
            }
            *(float4*)(out0 + (size_t)j * CSTR)     = o0;
            *(float4*)(out0 + (size_t)j * CSTR + 4) = o1;
            if (has1) {
                *(float4*)(out1 + (size_t)j * CSTR)     = q0;
                *(float4*)(out1 + (size_t)j * CSTR + 4) = q1;
            }
        }
    }
}

extern "C" void kernel_launch(void* const* d_in, const int* in_sizes, int n_in,
                              void* d_out, int out_size, void* d_ws, size_t ws_size,
                              hipStream_t stream) {
    const float* x1 = (const float*)d_in[0];
    const float* x2 = (const float*)d_in[1];
    float* out = (float*)d_out;

    // 1-D grid, XCD-pinned decode inside the kernel: 72 r2 x 4 b x 8 slots x 6 z.
    dim3 grid(72 * 4 * 8 * 6, 1, 1);   // 13824 blocks
    dim3 block(256, 1, 1);
    corr_kernel<<<grid, block, 0, stream>>>(x1, x2, out);
}

// Round 7
// 359.521 us; speedup vs baseline: 1.5864x; 1.5864x over previous
//
#include <hip/hip_runtime.h>
#include <stdint.h>

// Problem constants (match reference)
#define BB     4
#define CC     32
#define HH     32
#define WW     1024
#define PATCH  21
#define RAD    10
#define PADW   20                 // DIL*RAD : max displacement
#define CHUNKC 2                  // channels staged per pass (R3/R5-proven envelope)
#define NP     (CC / CHUNKC)      // 16 passes
#define NGR    266                // float4 granules per padded row ((1024+40)/4)
#define ROWF   (NGR * 4)          // 1064 floats per channel row
#define BUFF   (CHUNKC * ROWF)    // 2128 floats per buffer (8.5 KB)
#define CSTR   (HH * WW)          // channel stride (also the out pj stride)

// R6 POST-MORTEM: launch_bounds (256,8) cut the VGPR cap to 64 -> allocator
// gave 32 and spilled (WRITE 496 MB = output + 265 MB scratch; 382 us).
// R7 = R5 body (proven VGPR=48, no spill, launch_bounds(256,5)) + R6's
// XCD-pinned 1-D dispatch decode (lid%8 = XCD = row%8, row = 4*r2i + b:
// all 48 sharers of one (b,r2) x2 row on one XCD within a 384-id window).
typedef __attribute__((address_space(3))) uint32_t lds_u32_t;
typedef __attribute__((address_space(1))) const uint32_t glb_u32_t;

// Involution on granule index: for 8 consecutive even (or odd) logical slots,
// sigma's image is a complete residue system mod 8 -> conflict-free b128 reads.
// Closed on the never-staged OOB slot set {0..4, 261..265} (264<->265).
__device__ __forceinline__ int swz(int s) { return s ^ ((s >> 3) & 1); }

// DMA CHUNKC channels of one x2 row into sbuf (linear LDS dest = wave-uniform
// base + lane*16; swizzle realized by fetching global granule swz(q) into
// physical slot q — rule #21). Fully-OOB granules skipped -> keep prologue zeros.
__device__ __forceinline__ void stage_dma(const float* __restrict__ src0,
                                          float* __restrict__ sbuf, int tid) {
#pragma unroll
    for (int t = 0; t < 3; t++) {
        const int idx = tid + t * 256;
        if (idx < CHUNKC * NGR) {
            const int c  = (idx >= NGR) ? 1 : 0;
            const int q  = idx - c * NGR;
            const int gq = swz(q);
            const int base_gran = (tid & ~63) + t * 256;   // wave-uniform
            lds_u32_t* dst = (lds_u32_t*)(sbuf + base_gran * 4);
            const float* src = src0 + (size_t)c * CSTR + (gq * 4 - PADW);
            if (gq >= 5 && gq <= 260)
                __builtin_amdgcn_global_load_lds((glb_u32_t*)src, dst, 16, 0, 0);
        }
    }
}

// Block: 256 threads = 128 w-positions (Wout=8) x 2 tap-halves.
// Work decode from 1-D lid (see header comment). Chain for fixed (b,r2):
// elements e -> (pi = pi_hi - e, h = h0 + 2e); slot s owns {2s, 2s+1}
// (h rows sharing x2 row r2). Taps: pj = 4z + 2*th2 + j, j in {0,1}.
__global__ __launch_bounds__(256, 5)
void corr_kernel(const float* __restrict__ x1, const float* __restrict__ x2,
                 float* __restrict__ out) {
    __shared__ float sx2[2 * BUFF + 16];   // +16: masked tap-21 over-read pad

    const int tid = threadIdx.x;
    const int tw  = tid & 127;
    const int th2 = tid >> 7;              // wave-uniform (waves 0,1 vs 2,3)

    // ---- dispatch decode: lid -> (r2, b, s, z) with XCD pinning ----
    const int lid    = blockIdx.x;         // 0..13823
    const int xcd    = lid & 7;            // target XCD slot (m09 round-robin)
    const int t8     = lid >> 3;           // 0..1727
    const int sharer = t8 % 48;            // 48 sharers of one (b,r2) row
    const int rowd   = t8 / 48;            // 0..35
    const int row    = rowd * 8 + xcd;     // 0..287 ; row = 4*r2i + b
    const int r2i    = row >> 2;           // 0..71
    const int b      = row & 3;
    const int s      = sharer & 7;         // chain pair-slot
    const int z      = sharer >> 3;        // tap group 0..5
    const int r2     = r2i - PADW;         // -20..51

    const int pi_hi = min(20, (r2 + 20) >> 1);
    const int pi_lo = max(0, (r2 - 10) >> 1);
    const int L     = pi_hi - pi_lo + 1;        // chain length (1..16)
    const int e0    = 2 * s;
    if (e0 >= L) return;                        // empty slot: uniform exit

    const int  pi0  = pi_hi - e0;
    const int  h0   = r2 + 20 - 2 * pi0;        // in [0,31] by construction
    const bool has1 = (e0 + 1) < L;
    const int  pi1  = pi0 - 1;
    const int  h1   = h0 + 2;

    const int  pjb    = 4 * z + 2 * th2;        // even tap base
    const bool st0    = (pjb     <= 20);        // false only z=5,th2=1
    const bool st1    = (pjb + 1 <= 20);        // false for z=5
    const bool active = st0;                    // inactive waves: stage+barrier only
    const int  w8     = tw * 8;

    float* out0 = out + (((size_t)(b * PATCH * PATCH + pi0 * PATCH + pjb)) * HH + h0) * WW + w8;
    float* out1 = out + (((size_t)(b * PATCH * PATCH + pi1 * PATCH + pjb)) * HH + h1) * WW + w8;

    if ((unsigned)r2 >= (unsigned)HH) {
        // x2 row OOB: these (h,pi) outputs are zero for ALL taps. No barriers run.
        float4 zv = make_float4(0.f, 0.f, 0.f, 0.f);
        if (active) {
#pragma unroll
            for (int j = 0; j < 2; j++) {
                if (j == 0 ? st0 : st1) {
                    *(float4*)(out0 + (size_t)j * CSTR)     = zv;
                    *(float4*)(out0 + (size_t)j * CSTR + 4) = zv;
                    if (has1) {
                        *(float4*)(out1 + (size_t)j * CSTR)     = zv;
                        *(float4*)(out1 + (size_t)j * CSTR + 4) = zv;
                    }
                }
            }
        }
        return;
    }

    // Prologue: zero never-staged OOB slots of all 4 rows (2 buf x 2 ch).
    if (tid < 40) {
        const int rr = tid / 10, g = tid % 10;
        const int slot = (g < 5) ? g : (256 + g);   // {0..4, 261..265}
        *(float4*)(sx2 + rr * ROWF + 4 * slot) = make_float4(0.f, 0.f, 0.f, 0.f);
    }

    // Window granule base: padded col p = 8*tw + 2*pjb + (k + 2j); gb = 2tw + pjb/2.
    const int g0 = active ? (2 * tw + 2 * z + th2) : (2 * tw);
    int ps0 = 4 * swz(g0), ps1 = 4 * swz(g0 + 1), ps2 = 4 * swz(g0 + 2);

    const float* x2base = x2 + ((size_t)(b * CC) * HH + r2) * WW;
    const float* x1p0   = x1 + ((size_t)(b * CC) * HH + h0) * WW + w8;
    const float* x1p1   = has1 ? (x1p0 + 2 * WW) : x1p0;   // clamp: unused if !has1

    stage_dma(x2base, sx2, tid);     // chunk 0 -> buf 0
    __syncthreads();                 // drains DMA + prologue zeros

    float acc0[2][8], acc1[2][8];
#pragma unroll
    for (int j = 0; j < 2; j++)
#pragma unroll
        for (int k = 0; k < 8; k++) { acc0[j][k] = 0.f; acc1[j][k] = 0.f; }

    for (int p = 0; p < NP; p++) {
        if (p + 1 < NP)   // issue next chunk's DMA before computing this one
            stage_dma(x2base + (size_t)(p + 1) * CHUNKC * CSTR,
                      sx2 + ((p + 1) & 1) * BUFF, tid);
        if (active) {
            const float* buf = sx2 + (p & 1) * BUFF;
#pragma unroll
            for (int c = 0; c < CHUNKC; c++) {
                const float* row_p = buf + c * ROWF;
                float win[12];
                *(float4*)&win[0] = *(const float4*)(row_p + ps0);
                *(float4*)&win[4] = *(const float4*)(row_p + ps1);
                *(float4*)&win[8] = *(const float4*)(row_p + ps2);

                const float* xa = x1p0 + (size_t)(CHUNKC * p + c) * CSTR;
                const float* xb = x1p1 + (size_t)(CHUNKC * p + c) * CSTR;
                float4 a00 = *(const float4*)xa, a01 = *(const float4*)(xa + 4);
                float4 a10 = *(const float4*)xb, a11 = *(const float4*)(xb + 4);
                const float a0[8] = {a00.x, a00.y, a00.z, a00.w, a01.x, a01.y, a01.z, a01.w};
                const float a1[8] = {a10.x, a10.y, a10.z, a10.w, a11.x, a11.y, a11.z, a11.w};

                // tap j, output w8+k -> window float k + 2j (static, max 9)
#pragma unroll
                for (int j = 0; j < 2; j++)
#pragma unroll
                    for (int k = 0; k < 8; k++) {
                        const float wv = win[k + 2 * j];
                        acc0[j][k] = fmaf(a0[k], wv, acc0[j][k]);
                        acc1[j][k] = fmaf(a1[k], wv, acc1[j][k]);
                    }
            }
        }
        if (p + 1 < NP) __syncthreads();
    }

    if (!active) return;

    const float inv_c = 1.0f / (float)CC;
#pragma unroll
    for (int j = 0; j < 2; j++) {
        if (j == 0 ? st0 : st1) {
            float4 o0, o1, q0, q1;
            float* po0 = (float*)&o0; float* po1 = (float*)&o1;
            float* pq0 = (float*)&q0; float* pq1 = (float*)&q1;
#pragma unroll
            for (int k = 0; k < 4; k++) {
                float v0 = acc0[j][k]     * inv_c;
                float v1 = acc0[j][4 + k] * inv_c;
                float u0 = acc1[j][k]     * inv_c;
                float u1 = acc1[j][4 + k] * inv_c;
                po0[k] = v0 > 0.f ? v0 : 0.1f * v0;
                po1[k] = v1 > 0.f ? v1 : 0.1f * v1;
                pq0[k] = u0 > 0.f ? u0 : 0.1f * u0;
                pq1[k] = u1 > 0.f ? u1 : 0.1f * u1;
            }
            *(float4*)(out0 + (size_t)j * CSTR)     = o0;
            *(float4*)(out0 + (size_t)j * CSTR + 4) = o1;
            if (has1) {
                *(float4*)(out1 + (size_t)j * CSTR)     = q0;
                *(float4*)(out1 + (size_t)j * CSTR + 4) = q1;
            }
        }
    }
}

extern "C" void kernel_launch(void* const* d_in, const int* in_sizes, int n_in,
                              void* d_out, int out_size, void* d_ws, size_t ws_size,
                              hipStream_t stream) {
    const float* x1 = (const float*)d_in[0];
    const float* x2 = (const float*)d_in[1];
    float* out = (float*)d_out;

    // 1-D grid, XCD-pinned decode inside the kernel: 72 r2 x 4 b x 8 slots x 6 z.
    dim3 grid(72 * 4 * 8 * 6, 1, 1);   // 13824 blocks
    dim3 block(256, 1, 1);
    corr_kernel<<<grid, block, 0, stream>>>(x1, x2, out);
}